// Round 16
// baseline (45.974 us; speedup 1.0000x reference)
//
#include <hip/hip_runtime.h>

// Problem constants: B=2, L=8192, D=1024, f32 in/out.
#define BB 2
#define LL 8192
#define DD 1024
#define NC 128        // time chunks
#define TT 64         // chunk length (2^6)
#define NQ (DD/4)     // 256 d-quads; one thread <-> one quad (16 B/lane)
#define FB 8          // fold batch (2 float4 per step -> 16 loads in flight)

// ph = exp(-(pr^2+pi^2)) * exp(i*atan2(pi,pr))
__device__ __forceinline__ void compute_ph(float pr, float pi, float& phr, float& phi) {
    float r2 = fmaf(pr, pr, pi * pi);
    float mag = expf(-r2);
    float r = sqrtf(r2);
    if (r > 1e-30f) {
        float inv = mag / r;
        phr = pr * inv;
        phi = pi * inv;
    } else {
        phr = mag;  // atan2(0,0)=0 -> phase 1+0i
        phi = 0.0f;
    }
}

// ---- float4 streaming macros (static indices; named buffers = dbl buffer) ----
#define QLD8(buf, g) \
    { _Pragma("unroll") for (int u = 0; u < 8; ++u) \
        buf[u] = xq[(size_t)((g) * 8 + u) * NQ]; }

#define QSTEP(c, xc) \
    { float nr = fmaf(ph##c##r, s##c##r, fmaf(-ph##c##i, s##c##i, q##c##r * (xc))); \
      float ni = fmaf(ph##c##i, s##c##r, fmaf( ph##c##r, s##c##i, q##c##i * (xc))); \
      s##c##r = nr; s##c##i = ni; }

// consume 8, no writeback (partial pass)
#define QCP8P(buf) \
    { _Pragma("unroll") for (int u = 0; u < 8; ++u) { \
        float4 xv = buf[u]; \
        QSTEP(0, xv.x) QSTEP(1, xv.y) QSTEP(2, xv.z) QSTEP(3, xv.w) } }

// consume 8, keep Re in buf for the store (final pass)
#define QCP8F(buf) \
    { _Pragma("unroll") for (int u = 0; u < 8; ++u) { \
        float4 xv = buf[u]; \
        QSTEP(0, xv.x) QSTEP(1, xv.y) QSTEP(2, xv.z) QSTEP(3, xv.w) \
        buf[u] = make_float4(s0r, s1r, s2r, s3r); } }

#define QST8(buf, g) \
    { _Pragma("unroll") for (int u = 0; u < 8; ++u) \
        oq[(size_t)((g) * 8 + u) * NQ] = buf[u]; }

// Pass 1: zero-init chunk end-state. Pure float4 read stream (8 groups of 8).
__global__ __launch_bounds__(256) void k_partial(
    const float* __restrict__ x,
    const float* __restrict__ pr, const float* __restrict__ pi,
    const float* __restrict__ qr, const float* __restrict__ qi,
    float4* __restrict__ partial)
{
    const int q = threadIdx.x;        // quad 0..255 (gridDim.x == 1)
    const int j = blockIdx.y;
    const int b = blockIdx.z;

    const float4 prv = ((const float4*)pr)[q], piv = ((const float4*)pi)[q];
    const float4 qrv = ((const float4*)qr)[q], qiv = ((const float4*)qi)[q];
    float ph0r, ph0i, ph1r, ph1i, ph2r, ph2i, ph3r, ph3i;
    compute_ph(prv.x, piv.x, ph0r, ph0i);
    compute_ph(prv.y, piv.y, ph1r, ph1i);
    compute_ph(prv.z, piv.z, ph2r, ph2i);
    compute_ph(prv.w, piv.w, ph3r, ph3i);
    const float q0r = qrv.x, q0i = qiv.x, q1r = qrv.y, q1i = qiv.y;
    const float q2r = qrv.z, q2i = qiv.z, q3r = qrv.w, q3i = qiv.w;

    const float4* xq = (const float4*)(x + ((size_t)b * LL + (size_t)j * TT) * DD) + q;

    float s0r = 0.f, s0i = 0.f, s1r = 0.f, s1i = 0.f;
    float s2r = 0.f, s2i = 0.f, s3r = 0.f, s3i = 0.f;

    float4 bufA[8], bufB[8];
    QLD8(bufA, 0);  QLD8(bufB, 1);
    QCP8P(bufA);    QLD8(bufA, 2);
    QCP8P(bufB);    QLD8(bufB, 3);
    QCP8P(bufA);    QLD8(bufA, 4);
    QCP8P(bufB);    QLD8(bufB, 5);
    QCP8P(bufA);    QLD8(bufA, 6);
    QCP8P(bufB);    QLD8(bufB, 7);
    QCP8P(bufA);
    QCP8P(bufB);

    // layout: [b][j][h][NQ]; h=0 -> ch 0,1 ; h=1 -> ch 2,3
    float4* pp = partial + ((size_t)(b * NC + j) * 2) * NQ + q;
    pp[0]  = make_float4(s0r, s0i, s1r, s1i);
    pp[NQ] = make_float4(s2r, s2i, s3r, s3i);
}

#define FSTEP(c, vr, vi) \
    { float nr = fmaf(a##c##r, S##c##r, fmaf(-a##c##i, S##c##i, vr)); \
      float ni = fmaf(a##c##i, S##c##r, fmaf( a##c##r, S##c##i, vi)); \
      S##c##r = nr; S##c##i = ni; }

// Pass 2: fold partials 0..j-1 (FB-deep clamped batches, uniform trip count),
// then replay the chunk as a float4 read+write stream (8 groups of 8).
__global__ __launch_bounds__(256) void k_final(
    const float* __restrict__ x,
    const float* __restrict__ pr, const float* __restrict__ pi,
    const float* __restrict__ qr, const float* __restrict__ qi,
    const float* __restrict__ lr, const float* __restrict__ li,
    const float4* __restrict__ partial,
    float* __restrict__ out)
{
    const int q = threadIdx.x;        // quad 0..255
    const int j = blockIdx.y;
    const int b = blockIdx.z;

    const float4 prv = ((const float4*)pr)[q], piv = ((const float4*)pi)[q];
    const float4 qrv = ((const float4*)qr)[q], qiv = ((const float4*)qi)[q];
    float ph0r, ph0i, ph1r, ph1i, ph2r, ph2i, ph3r, ph3i;
    compute_ph(prv.x, piv.x, ph0r, ph0i);
    compute_ph(prv.y, piv.y, ph1r, ph1i);
    compute_ph(prv.z, piv.z, ph2r, ph2i);
    compute_ph(prv.w, piv.w, ph3r, ph3i);
    const float q0r = qrv.x, q0i = qiv.x, q1r = qrv.y, q1i = qiv.y;
    const float q2r = qrv.z, q2i = qiv.z, q3r = qrv.w, q3i = qiv.w;

    // a = ph^TT per channel (TT = 2^6 -> 6 squarings)
    float a0r = ph0r, a0i = ph0i, a1r = ph1r, a1i = ph1i;
    float a2r = ph2r, a2i = ph2i, a3r = ph3r, a3i = ph3i;
    #pragma unroll
    for (int k = 0; k < 6; ++k) {
        float n0r = a0r*a0r - a0i*a0i, n0i = 2.f*a0r*a0i;
        float n1r = a1r*a1r - a1i*a1i, n1i = 2.f*a1r*a1i;
        float n2r = a2r*a2r - a2i*a2i, n2i = 2.f*a2r*a2i;
        float n3r = a3r*a3r - a3i*a3i, n3i = 2.f*a3r*a3i;
        a0r = n0r; a0i = n0i; a1r = n1r; a1i = n1i;
        a2r = n2r; a2i = n2i; a3r = n3r; a3i = n3i;
    }

    const float4 lrv = ((const float4*)lr)[q], liv = ((const float4*)li)[q];
    float S0r = lrv.x, S0i = liv.x, S1r = lrv.y, S1i = liv.y;
    float S2r = lrv.z, S2i = liv.z, S3r = lrv.w, S3i = liv.w;

    // fold: S <- a*S + P_k, k = 0..j-1 (clamped batched loads, uniform guard)
    const float4* pb = partial + ((size_t)b * NC * 2) * NQ + q;
    for (int bs = 0; bs < j; bs += FB) {
        float4 bufA[FB], bufB[FB];
        #pragma unroll
        for (int u = 0; u < FB; ++u) {
            int k = bs + u;
            int kc = (k < j) ? k : (j - 1);
            bufA[u] = pb[(size_t)kc * 2 * NQ];
            bufB[u] = pb[(size_t)kc * 2 * NQ + NQ];
        }
        #pragma unroll
        for (int u = 0; u < FB; ++u) {
            if (bs + u < j) {
                FSTEP(0, bufA[u].x, bufA[u].y)
                FSTEP(1, bufA[u].z, bufA[u].w)
                FSTEP(2, bufB[u].x, bufB[u].y)
                FSTEP(3, bufB[u].z, bufB[u].w)
            }
        }
    }
    float s0r = S0r, s0i = S0i, s1r = S1r, s1i = S1i;
    float s2r = S2r, s2i = S2i, s3r = S3r, s3i = S3i;

    // replay chunk from true start state; double-buffered load/compute/store
    const size_t rowbase = (size_t)b * LL + (size_t)j * TT;
    const float4* xq = (const float4*)(x + rowbase * DD) + q;
    float4* oq = (float4*)(out + rowbase * DD) + q;

    float4 bufA[8], bufB[8];
    QLD8(bufA, 0);  QLD8(bufB, 1);
    QCP8F(bufA);  QST8(bufA, 0);  QLD8(bufA, 2);
    QCP8F(bufB);  QST8(bufB, 1);  QLD8(bufB, 3);
    QCP8F(bufA);  QST8(bufA, 2);  QLD8(bufA, 4);
    QCP8F(bufB);  QST8(bufB, 3);  QLD8(bufB, 5);
    QCP8F(bufA);  QST8(bufA, 4);  QLD8(bufA, 6);
    QCP8F(bufB);  QST8(bufB, 5);  QLD8(bufB, 7);
    QCP8F(bufA);  QST8(bufA, 6);
    QCP8F(bufB);  QST8(bufB, 7);
}

extern "C" void kernel_launch(void* const* d_in, const int* in_sizes, int n_in,
                              void* d_out, int out_size, void* d_ws, size_t ws_size,
                              hipStream_t stream) {
    const float* x  = (const float*)d_in[0];
    const float* pr = (const float*)d_in[1];
    const float* pi = (const float*)d_in[2];
    const float* qr = (const float*)d_in[3];
    const float* qi = (const float*)d_in[4];
    const float* lr = (const float*)d_in[5];
    const float* li = (const float*)d_in[6];
    float* out = (float*)d_out;

    float4* partial = (float4*)d_ws;   // BB*NC*2*NQ float4 = 2 MB

    dim3 grid(1, NC, BB);              // 256 blocks of 256 threads
    k_partial<<<grid, 256, 0, stream>>>(x, pr, pi, qr, qi, partial);
    k_final<<<grid, 256, 0, stream>>>(x, pr, pi, qr, qi, lr, li, partial, out);
}

// Round 17
// 43.496 us; speedup vs baseline: 1.0570x; 1.0570x over previous
//
#include <hip/hip_runtime.h>

// Problem constants: B=2, L=8192, D=1024, f32 in/out.
#define BB 2
#define LL 8192
#define DD 1024
#define NC 128        // time chunks
#define TT 64         // chunk length (2^6)
#define NG 16         // chunk groups (8 chunks per group)
#define GSZ 8
#define NPAIR (DD/2)  // 512 d-pairs; one thread <-> one d-pair (8 B/lane)

// ph = exp(-(pr^2+pi^2)) * exp(i*atan2(pi,pr))
__device__ __forceinline__ void compute_ph(float pr, float pi, float& phr, float& phi) {
    float r2 = fmaf(pr, pr, pi * pi);
    float mag = expf(-r2);
    float r = sqrtf(r2);
    if (r > 1e-30f) {
        float inv = mag / r;
        phr = pr * inv;
        phi = pi * inv;
    } else {
        phr = mag;  // atan2(0,0)=0 -> phase 1+0i
        phi = 0.0f;
    }
}

// ---- 8-deep streaming macros (static indices; named buffers = dbl buffer) ----
#define LD8(buf, g) \
    { _Pragma("unroll") for (int u = 0; u < 8; ++u) \
        buf[u] = xp[(size_t)((g) * 8 + u) * NPAIR]; }

#define CP8P(buf) \
    { _Pragma("unroll") for (int u = 0; u < 8; ++u) { \
        float2 xv = buf[u]; \
        float nr0 = fmaf(phr0, s0r, fmaf(-phi0, s0i, q0r * xv.x)); \
        float ni0 = fmaf(phi0, s0r, fmaf( phr0, s0i, q0i * xv.x)); \
        float nr1 = fmaf(phr1, s1r, fmaf(-phi1, s1i, q1r * xv.y)); \
        float ni1 = fmaf(phi1, s1r, fmaf( phr1, s1i, q1i * xv.y)); \
        s0r = nr0; s0i = ni0; s1r = nr1; s1i = ni1; } }

#define CP8F(buf) \
    { _Pragma("unroll") for (int u = 0; u < 8; ++u) { \
        float2 xv = buf[u]; \
        float nr0 = fmaf(phr0, s0r, fmaf(-phi0, s0i, q0r * xv.x)); \
        float ni0 = fmaf(phi0, s0r, fmaf( phr0, s0i, q0i * xv.x)); \
        float nr1 = fmaf(phr1, s1r, fmaf(-phi1, s1i, q1r * xv.y)); \
        float ni1 = fmaf(phi1, s1r, fmaf( phr1, s1i, q1i * xv.y)); \
        s0r = nr0; s0i = ni0; s1r = nr1; s1i = ni1; \
        buf[u] = make_float2(nr0, nr1); } }

#define ST8(buf, g) \
    { _Pragma("unroll") for (int u = 0; u < 8; ++u) \
        op[(size_t)((g) * 8 + u) * NPAIR] = buf[u]; }

// complex fold step: S <- a*S + (vr,vi), channels 0/1
#define FOLD0(ar_, ai_, vr, vi) \
    { float nr = fmaf(ar_, s0r, fmaf(-(ai_), s0i, vr)); \
      float ni = fmaf(ai_, s0r, fmaf( (ar_), s0i, vi)); \
      s0r = nr; s0i = ni; }
#define FOLD1(ar_, ai_, vr, vi) \
    { float nr = fmaf(ar_, s1r, fmaf(-(ai_), s1i, vr)); \
      float ni = fmaf(ai_, s1r, fmaf( (ar_), s1i, vi)); \
      s1r = nr; s1i = ni; }

// Pass 1: zero-init chunk end-state (read stream over x, TT=64 -> 8 groups).
__global__ __launch_bounds__(256) void k_partial(
    const float* __restrict__ x,
    const float* __restrict__ pr, const float* __restrict__ pi,
    const float* __restrict__ qr, const float* __restrict__ qi,
    float4* __restrict__ partial)
{
    const int p = blockIdx.x * 256 + threadIdx.x;   // d-pair 0..511
    const int j = blockIdx.y;
    const int b = blockIdx.z;
    const int d0 = 2 * p, d1 = d0 + 1;

    float phr0, phi0, phr1, phi1;
    compute_ph(pr[d0], pi[d0], phr0, phi0);
    compute_ph(pr[d1], pi[d1], phr1, phi1);
    const float q0r = qr[d0], q0i = qi[d0], q1r = qr[d1], q1i = qi[d1];

    const float2* xp = (const float2*)(x + ((size_t)b * LL + (size_t)j * TT) * DD) + p;

    float s0r = 0.f, s0i = 0.f, s1r = 0.f, s1i = 0.f;
    float2 bufA[8], bufB[8];
    LD8(bufA, 0);  LD8(bufB, 1);
    CP8P(bufA);    LD8(bufA, 2);
    CP8P(bufB);    LD8(bufB, 3);
    CP8P(bufA);    LD8(bufA, 4);
    CP8P(bufB);    LD8(bufB, 5);
    CP8P(bufA);    LD8(bufA, 6);
    CP8P(bufB);    LD8(bufB, 7);
    CP8P(bufA);
    CP8P(bufB);

    partial[((size_t)b * NC + j) * NPAIR + p] = make_float4(s0r, s0i, s1r, s1i);
}

// Pass 1.5 (tiny): group aggregates Q_g = zero-init fold of the group's 8
// partials with decay a = ph^TT. 16384 threads; 8 independent loads each.
__global__ __launch_bounds__(256) void k_agg(
    const float* __restrict__ pr, const float* __restrict__ pi,
    const float4* __restrict__ partial,
    float4* __restrict__ Q)
{
    const int idx = blockIdx.x * 256 + threadIdx.x;  // 0..16383
    const int p = idx & (NPAIR - 1);
    const int rest = idx >> 9;
    const int g = rest & (NG - 1);
    const int b = rest >> 4;
    const int d0 = 2 * p, d1 = d0 + 1;

    float phr0, phi0, phr1, phi1;
    compute_ph(pr[d0], pi[d0], phr0, phi0);
    compute_ph(pr[d1], pi[d1], phr1, phi1);
    // a = ph^TT (6 squarings)
    float a0r = phr0, a0i = phi0, a1r = phr1, a1i = phi1;
    #pragma unroll
    for (int k = 0; k < 6; ++k) {
        float n0r = a0r*a0r - a0i*a0i, n0i = 2.f*a0r*a0i;
        float n1r = a1r*a1r - a1i*a1i, n1i = 2.f*a1r*a1i;
        a0r = n0r; a0i = n0i; a1r = n1r; a1i = n1i;
    }

    const float4* pb = partial + ((size_t)b * NC + (size_t)g * GSZ) * NPAIR + p;
    float4 Pm[GSZ];
    #pragma unroll
    for (int m = 0; m < GSZ; ++m) Pm[m] = pb[(size_t)m * NPAIR];

    float s0r = 0.f, s0i = 0.f, s1r = 0.f, s1i = 0.f;
    #pragma unroll
    for (int m = 0; m < GSZ; ++m) {
        FOLD0(a0r, a0i, Pm[m].x, Pm[m].y)
        FOLD1(a1r, a1i, Pm[m].z, Pm[m].w)
    }
    Q[((size_t)b * NG + g) * NPAIR + p] = make_float4(s0r, s0i, s1r, s1i);
}

// Pass 2: two-level fold (<=15 group aggregates with A=a^8, then <=7 fine
// partials with a), then replay the chunk as a double-buffered r+w stream.
__global__ __launch_bounds__(256) void k_final(
    const float* __restrict__ x,
    const float* __restrict__ pr, const float* __restrict__ pi,
    const float* __restrict__ qr, const float* __restrict__ qi,
    const float* __restrict__ lr, const float* __restrict__ li,
    const float4* __restrict__ partial,
    const float4* __restrict__ Q,
    float* __restrict__ out)
{
    const int p = blockIdx.x * 256 + threadIdx.x;   // d-pair 0..511
    const int j = blockIdx.y;
    const int b = blockIdx.z;
    const int d0 = 2 * p, d1 = d0 + 1;
    const int g = j >> 3;          // group index (0..15)
    const int r = j & 7;           // position within group

    float phr0, phi0, phr1, phi1;
    compute_ph(pr[d0], pi[d0], phr0, phi0);
    compute_ph(pr[d1], pi[d1], phr1, phi1);
    const float q0r = qr[d0], q0i = qi[d0], q1r = qr[d1], q1i = qi[d1];

    // a = ph^TT (6 squarings); A = a^8 (3 more)
    float a0r = phr0, a0i = phi0, a1r = phr1, a1i = phi1;
    #pragma unroll
    for (int k = 0; k < 6; ++k) {
        float n0r = a0r*a0r - a0i*a0i, n0i = 2.f*a0r*a0i;
        float n1r = a1r*a1r - a1i*a1i, n1i = 2.f*a1r*a1i;
        a0r = n0r; a0i = n0i; a1r = n1r; a1i = n1i;
    }
    float A0r = a0r, A0i = a0i, A1r = a1r, A1i = a1i;
    #pragma unroll
    for (int k = 0; k < 3; ++k) {
        float n0r = A0r*A0r - A0i*A0i, n0i = 2.f*A0r*A0i;
        float n1r = A1r*A1r - A1i*A1i, n1i = 2.f*A1r*A1i;
        A0r = n0r; A0i = n0i; A1r = n1r; A1i = n1i;
    }

    float s0r = lr[d0], s0i = li[d0], s1r = lr[d1], s1i = li[d1];

    // level-1 fold: T_g = fold of Q_0..Q_{g-1} with A, from last (g <= 15)
    if (g > 0) {
        const float4* qb = Q + (size_t)b * NG * NPAIR + p;
        float4 buf[16];
        #pragma unroll
        for (int u = 0; u < 16; ++u) {
            int kc = (u < g) ? u : 0;                // clamped valid address
            buf[u] = qb[(size_t)kc * NPAIR];
        }
        #pragma unroll
        for (int u = 0; u < 16; ++u) {
            if (u < g) {                              // uniform per block
                FOLD0(A0r, A0i, buf[u].x, buf[u].y)
                FOLD1(A1r, A1i, buf[u].z, buf[u].w)
            }
        }
    }

    // level-2 fold: fine partials within the group (r <= 7), with a
    if (r > 0) {
        const float4* pb = partial + ((size_t)b * NC + (size_t)g * GSZ) * NPAIR + p;
        float4 buf[8];
        #pragma unroll
        for (int u = 0; u < 8; ++u) {
            int kc = (u < r) ? u : 0;
            buf[u] = pb[(size_t)kc * NPAIR];
        }
        #pragma unroll
        for (int u = 0; u < 8; ++u) {
            if (u < r) {
                FOLD0(a0r, a0i, buf[u].x, buf[u].y)
                FOLD1(a1r, a1i, buf[u].z, buf[u].w)
            }
        }
    }

    // replay chunk from true start state; double-buffered load/compute/store
    const size_t rowbase = (size_t)b * LL + (size_t)j * TT;
    const float2* xp = (const float2*)(x + rowbase * DD) + p;
    float2* op = (float2*)(out + rowbase * DD) + p;

    float2 bufA[8], bufB[8];
    LD8(bufA, 0);  LD8(bufB, 1);
    CP8F(bufA);  ST8(bufA, 0);  LD8(bufA, 2);
    CP8F(bufB);  ST8(bufB, 1);  LD8(bufB, 3);
    CP8F(bufA);  ST8(bufA, 2);  LD8(bufA, 4);
    CP8F(bufB);  ST8(bufB, 3);  LD8(bufB, 5);
    CP8F(bufA);  ST8(bufA, 4);  LD8(bufA, 6);
    CP8F(bufB);  ST8(bufB, 5);  LD8(bufB, 7);
    CP8F(bufA);  ST8(bufA, 6);
    CP8F(bufB);  ST8(bufB, 7);
}

extern "C" void kernel_launch(void* const* d_in, const int* in_sizes, int n_in,
                              void* d_out, int out_size, void* d_ws, size_t ws_size,
                              hipStream_t stream) {
    const float* x  = (const float*)d_in[0];
    const float* pr = (const float*)d_in[1];
    const float* pi = (const float*)d_in[2];
    const float* qr = (const float*)d_in[3];
    const float* qi = (const float*)d_in[4];
    const float* lr = (const float*)d_in[5];
    const float* li = (const float*)d_in[6];
    float* out = (float*)d_out;

    float4* partial = (float4*)d_ws;                       // BB*NC*NPAIR*16 = 2 MB
    float4* Q       = partial + (size_t)BB * NC * NPAIR;   // BB*NG*NPAIR*16 = 256 KB

    dim3 grid(NPAIR / 256, NC, BB);    // 2 x 128 x 2 = 512 blocks (8 waves/CU)
    k_partial<<<grid, 256, 0, stream>>>(x, pr, pi, qr, qi, partial);
    k_agg<<<(BB * NG * NPAIR) / 256, 256, 0, stream>>>(pr, pi, partial, Q);
    k_final<<<grid, 256, 0, stream>>>(x, pr, pi, qr, qi, lr, li, partial, Q, out);
}

// Round 18
// 40.652 us; speedup vs baseline: 1.1309x; 1.0700x over previous
//
#include <hip/hip_runtime.h>

// Problem constants: B=2, L=8192, D=1024, f32 in/out.
#define BB 2
#define LL 8192
#define DD 1024
#define NC 64         // time chunks (fold traffic ~ NC^2 -> keep small)
#define TT 128        // chunk length (2^7)
#define NPAIR (DD/2)  // pass1: one thread <-> one d-pair (8 B/lane)
#define FOLD_BATCH 16

// ph = exp(-(pr^2+pi^2)) * exp(i*atan2(pi,pr))
__device__ __forceinline__ void compute_ph(float pr, float pi, float& phr, float& phi) {
    float r2 = fmaf(pr, pr, pi * pi);
    float mag = expf(-r2);
    float r = sqrtf(r2);
    if (r > 1e-30f) {
        float inv = mag / r;
        phr = pr * inv;
        phi = pi * inv;
    } else {
        phr = mag;  // atan2(0,0)=0 -> phase 1+0i
        phi = 0.0f;
    }
}

// ---- pass-1 macros: float2 lanes (pair), 8-deep double buffer ----
#define LD8(buf, g) \
    { _Pragma("unroll") for (int u = 0; u < 8; ++u) \
        buf[u] = xp[(size_t)((g) * 8 + u) * NPAIR]; }

#define CP8P(buf) \
    { _Pragma("unroll") for (int u = 0; u < 8; ++u) { \
        float2 xv = buf[u]; \
        float nr0 = fmaf(phr0, s0r, fmaf(-phi0, s0i, q0r * xv.x)); \
        float ni0 = fmaf(phi0, s0r, fmaf( phr0, s0i, q0i * xv.x)); \
        float nr1 = fmaf(phr1, s1r, fmaf(-phi1, s1i, q1r * xv.y)); \
        float ni1 = fmaf(phi1, s1r, fmaf( phr1, s1i, q1i * xv.y)); \
        s0r = nr0; s0i = ni0; s1r = nr1; s1i = ni1; } }

// ---- pass-2 macros: scalar lanes (single d), 8-deep double buffer ----
#define SLD8(buf, g) \
    { _Pragma("unroll") for (int u = 0; u < 8; ++u) \
        buf[u] = xp[(size_t)((g) * 8 + u) * DD]; }

#define SCP8F(buf) \
    { _Pragma("unroll") for (int u = 0; u < 8; ++u) { \
        float xv = buf[u]; \
        float nr = fmaf(phr, sr, fmaf(-phi, si, qre * xv)); \
        float ni = fmaf(phi, sr, fmaf( phr, si, qim * xv)); \
        sr = nr; si = ni; \
        buf[u] = nr; } }

#define SST8(buf, g) \
    { _Pragma("unroll") for (int u = 0; u < 8; ++u) \
        op[(size_t)((g) * 8 + u) * DD] = buf[u]; }

// Pass 1: zero-init chunk end-state (read stream over x, 16 groups of 8).
// partial layout: float2 per (b, j, d) -> [b][j][DD]; pair-thread writes
// its two adjacent float2s as one aligned float4 (16 B/lane, coalesced).
__global__ __launch_bounds__(256) void k_partial(
    const float* __restrict__ x,
    const float* __restrict__ pr, const float* __restrict__ pi,
    const float* __restrict__ qr, const float* __restrict__ qi,
    float2* __restrict__ partial)
{
    const int p = blockIdx.x * 256 + threadIdx.x;   // d-pair 0..511
    const int j = blockIdx.y;
    const int b = blockIdx.z;
    const int d0 = 2 * p, d1 = d0 + 1;

    float phr0, phi0, phr1, phi1;
    compute_ph(pr[d0], pi[d0], phr0, phi0);
    compute_ph(pr[d1], pi[d1], phr1, phi1);
    const float q0r = qr[d0], q0i = qi[d0], q1r = qr[d1], q1i = qi[d1];

    const float2* xp = (const float2*)(x + ((size_t)b * LL + (size_t)j * TT) * DD) + p;

    float s0r = 0.f, s0i = 0.f, s1r = 0.f, s1i = 0.f;
    float2 bufA[8], bufB[8];
    LD8(bufA, 0);  LD8(bufB, 1);
    CP8P(bufA);    LD8(bufA, 2);
    CP8P(bufB);    LD8(bufB, 3);
    CP8P(bufA);    LD8(bufA, 4);
    CP8P(bufB);    LD8(bufB, 5);
    CP8P(bufA);    LD8(bufA, 6);
    CP8P(bufB);    LD8(bufB, 7);
    CP8P(bufA);    LD8(bufA, 8);
    CP8P(bufB);    LD8(bufB, 9);
    CP8P(bufA);    LD8(bufA, 10);
    CP8P(bufB);    LD8(bufB, 11);
    CP8P(bufA);    LD8(bufA, 12);
    CP8P(bufB);    LD8(bufB, 13);
    CP8P(bufA);    LD8(bufA, 14);
    CP8P(bufB);    LD8(bufB, 15);
    CP8P(bufA);
    CP8P(bufB);

    float4* pp = (float4*)(partial + ((size_t)b * NC + j) * DD + d0);
    *pp = make_float4(s0r, s0i, s1r, s1i);
}

// Pass 2: scalar lanes (one thread per d) -> 512 blocks = 2 waves/SIMD.
// Fold partials 0..j-1 (16-deep clamped batches), then replay the chunk
// as a double-buffered 4 B/lane read + write stream (wave = 256 B lines).
__global__ __launch_bounds__(256) void k_final(
    const float* __restrict__ x,
    const float* __restrict__ pr, const float* __restrict__ pi,
    const float* __restrict__ qr, const float* __restrict__ qi,
    const float* __restrict__ lr, const float* __restrict__ li,
    const float2* __restrict__ partial,
    float* __restrict__ out)
{
    const int d = blockIdx.x * 256 + threadIdx.x;   // 0..1023
    const int j = blockIdx.y;
    const int b = blockIdx.z;

    float phr, phi; compute_ph(pr[d], pi[d], phr, phi);
    const float qre = qr[d], qim = qi[d];

    // a = ph^TT by repeated squaring (TT = 2^7)
    float ar = phr, ai = phi;
    #pragma unroll
    for (int k = 0; k < 7; ++k) {
        float nr = ar * ar - ai * ai;
        float ni = 2.f * ar * ai;
        ar = nr; ai = ni;
    }

    // fold: S = last; S <- a*S + P_k for k = 0..j-1 (uniform trip count)
    float sr = lr[d], si = li[d];
    const float2* pb = partial + (size_t)b * NC * DD + d;
    for (int bs = 0; bs < j; bs += FOLD_BATCH) {
        float2 buf[FOLD_BATCH];
        #pragma unroll
        for (int u = 0; u < FOLD_BATCH; ++u) {
            int k = bs + u;
            int kc = (k < j) ? k : (j - 1);   // clamp: always a valid address
            buf[u] = pb[(size_t)kc * DD];
        }
        #pragma unroll
        for (int u = 0; u < FOLD_BATCH; ++u) {
            int k = bs + u;
            if (k < j) {
                float nr = fmaf(ar, sr, fmaf(-ai, si, buf[u].x));
                float ni = fmaf(ai, sr, fmaf( ar, si, buf[u].y));
                sr = nr; si = ni;
            }
        }
    }

    // replay chunk from true start state; double-buffered load/compute/store
    const size_t base = ((size_t)b * LL + (size_t)j * TT) * DD + d;
    const float* xp = x + base;
    float* op = out + base;

    float bufA[8], bufB[8];
    SLD8(bufA, 0);  SLD8(bufB, 1);
    SCP8F(bufA);  SST8(bufA, 0);  SLD8(bufA, 2);
    SCP8F(bufB);  SST8(bufB, 1);  SLD8(bufB, 3);
    SCP8F(bufA);  SST8(bufA, 2);  SLD8(bufA, 4);
    SCP8F(bufB);  SST8(bufB, 3);  SLD8(bufB, 5);
    SCP8F(bufA);  SST8(bufA, 4);  SLD8(bufA, 6);
    SCP8F(bufB);  SST8(bufB, 5);  SLD8(bufB, 7);
    SCP8F(bufA);  SST8(bufA, 6);  SLD8(bufA, 8);
    SCP8F(bufB);  SST8(bufB, 7);  SLD8(bufB, 9);
    SCP8F(bufA);  SST8(bufA, 8);  SLD8(bufA, 10);
    SCP8F(bufB);  SST8(bufB, 9);  SLD8(bufB, 11);
    SCP8F(bufA);  SST8(bufA, 10); SLD8(bufA, 12);
    SCP8F(bufB);  SST8(bufB, 11); SLD8(bufB, 13);
    SCP8F(bufA);  SST8(bufA, 12); SLD8(bufA, 14);
    SCP8F(bufB);  SST8(bufB, 13); SLD8(bufB, 15);
    SCP8F(bufA);  SST8(bufA, 14);
    SCP8F(bufB);  SST8(bufB, 15);
}

extern "C" void kernel_launch(void* const* d_in, const int* in_sizes, int n_in,
                              void* d_out, int out_size, void* d_ws, size_t ws_size,
                              hipStream_t stream) {
    const float* x  = (const float*)d_in[0];
    const float* pr = (const float*)d_in[1];
    const float* pi = (const float*)d_in[2];
    const float* qr = (const float*)d_in[3];
    const float* qi = (const float*)d_in[4];
    const float* lr = (const float*)d_in[5];
    const float* li = (const float*)d_in[6];
    float* out = (float*)d_out;

    float2* partial = (float2*)d_ws;   // BB*NC*DD float2 = 1 MB

    dim3 grid1(NPAIR / 256, NC, BB);   // 2 x 64 x 2 = 256 blocks (pass 1)
    dim3 grid2(DD / 256, NC, BB);      // 4 x 64 x 2 = 512 blocks (pass 2)
    k_partial<<<grid1, 256, 0, stream>>>(x, pr, pi, qr, qi, partial);
    k_final<<<grid2, 256, 0, stream>>>(x, pr, pi, qr, qi, lr, li, partial, out);
}